// Round 10
// baseline (32.906 us; speedup 1.0000x reference)
//
#include <hip/hip_runtime.h>
#include <math.h>

#define BSZ   65536
#define INP   16
#define HL    10
#define NL    3
#define TT    200
#define NPOP  8600000.0f
#define ROWB  (BSZ * 4u)     // bytes per t-row of out
#define CH    16
#define NCH   12             // 12*16 + 7 = 199 steps

typedef float f32x4 __attribute__((ext_vector_type(4)));

__device__ __forceinline__ float fast_tanh(float x) {
    float e = exp2f(x * 2.8853900817779268f);
    return 1.0f - 2.0f * __builtin_amdgcn_rcpf(e + 1.0f);
}

// ---------------- Kernel A: parameter nets, one thread per (sample, net) ----
__global__ __launch_bounds__(256) void mlp_kernel(
    const float* __restrict__ data,
    const float* __restrict__ W0,  const float* __restrict__ b0,
    const float* __restrict__ Wh,  const float* __restrict__ bh,
    const float* __restrict__ Wo,  const float* __restrict__ bo,
    float* __restrict__ vals)         // 3 x B
{
    const int n   = blockIdx.y;
    const int tid = threadIdx.x;

    __shared__ float sW0[HL * INP];
    __shared__ float sb0[HL];
    __shared__ float sWh[NL * HL * HL];
    __shared__ float sbh[NL * HL];
    __shared__ float sWo[HL];
    __shared__ float sbo;

    for (int i = tid; i < HL * INP;      i += 256) sW0[i] = W0[n * HL * INP + i];
    for (int i = tid; i < HL;            i += 256) sb0[i] = b0[n * HL + i];
    for (int i = tid; i < NL * HL * HL;  i += 256) sWh[i] = Wh[n * NL * HL * HL + i];
    for (int i = tid; i < NL * HL;       i += 256) sbh[i] = bh[n * NL * HL + i];
    for (int i = tid; i < HL;            i += 256) sWo[i] = Wo[n * HL + i];
    if (tid == 0) sbo = bo[n];
    __syncthreads();

    const int b = blockIdx.x * 256 + tid;

    float x[INP];
    const float4* xin = reinterpret_cast<const float4*>(data + (size_t)b * INP);
    #pragma unroll
    for (int q = 0; q < INP / 4; ++q) {
        float4 v = xin[q];
        x[q * 4 + 0] = v.x; x[q * 4 + 1] = v.y;
        x[q * 4 + 2] = v.z; x[q * 4 + 3] = v.w;
    }

    float h[HL];
    #pragma unroll
    for (int k = 0; k < HL; ++k) {
        float acc = sb0[k];
        #pragma unroll
        for (int i = 0; i < INP; ++i)
            acc = fmaf(x[i], sW0[k * INP + i], acc);
        h[k] = fast_tanh(acc);
    }
    #pragma unroll
    for (int l = 0; l < NL; ++l) {
        float h2[HL];
        #pragma unroll
        for (int k = 0; k < HL; ++k) {
            float acc = sbh[l * HL + k];
            #pragma unroll
            for (int i = 0; i < HL; ++i)
                acc = fmaf(h[i], sWh[(l * HL + k) * HL + i], acc);
            h2[k] = fast_tanh(acc);
        }
        #pragma unroll
        for (int k = 0; k < HL; ++k) h[k] = h2[k];
    }
    float acc = sbo;
    #pragma unroll
    for (int i = 0; i < HL; ++i)
        acc = fmaf(h[i], sWo[i], acc);

    vals[(size_t)n * BSZ + b] = fmaxf(acc, 0.0f) + log1pf(expf(-fabsf(acc)));
}

// ---------------- Kernel B: RK4, LDS-staged burst dwordx4 store path --------
#define ST4(VOFF, VAL) \
    asm volatile("global_store_dwordx4 %0, %1, %2" \
                 :: "v"(VOFF), "v"(VAL), "s"(out) : "memory")

__global__ __launch_bounds__(256, 1) void sir_kernel(
    const float* __restrict__ vals,   // 3 x B
    const float* __restrict__ times,  // T
    float* __restrict__ out)          // T x B
{
    const int tid = threadIdx.x;
    const int b   = blockIdx.x * 256 + tid;
    const int w   = tid >> 6;         // wave id in block (0..3)
    const int l   = tid & 63;         // lane

    const float gamma = vals[b];
    const float beta  = vals[BSZ + b];
    const float I0    = vals[2 * BSZ + b];

    __shared__ float sdt[208];          // dt table (52 float4s, zero-padded)
    __shared__ float sbuf[2][CH][256];  // I staging, double-buffered (32 KB)

    if (tid < TT - 1)   sdt[tid] = times[tid + 1] - times[tid];
    else if (tid < 208) sdt[tid] = 0.0f;
    __syncthreads();                  // pre-loop; no asm stores in flight yet

    float S = NPOP - I0;
    float I = I0;
    const float bn = beta * (1.0f / NPOP);

    // t = 0 row via asm store: keeps compiler from vmcnt-guarding I's register
    {
        unsigned v0 = (unsigned)b * 4u;
        asm volatile("global_store_dword %0, %1, %2"
                     :: "v"(v0), "v"(I), "s"(out) : "memory");
    }

    auto step = [&](float dt) {
        const float hdt = 0.5f * dt;
        float f1 = (bn * S) * I;
        float r1 = gamma * I;
        float m1 = f1 - r1;
        float aS = fmaf(-hdt, f1, S), aI = fmaf(hdt, m1, I);
        float f2 = (bn * aS) * aI;
        float r2 = gamma * aI;
        float m2 = f2 - r2;
        float bS = fmaf(-hdt, f2, S), bI = fmaf(hdt, m2, I);
        float f3 = (bn * bS) * bI;
        float r3 = gamma * bI;
        float m3 = f3 - r3;
        float cS = fmaf(-dt, f3, S),  cI = fmaf(dt, m3, I);
        float f4 = (bn * cS) * cI;
        float r4 = gamma * cI;
        float m4 = f4 - r4;
        const float c6 = dt * (1.0f / 6.0f);
        S = fmaf(-c6, (f1 + f4) + 2.0f * (f2 + f3), S);
        I = fmaf( c6, (m1 + m4) + 2.0f * (m2 + m3), I);
    };

    const float4* sdt4 = reinterpret_cast<const float4*>(sdt);

    // burst-store byte offsets: row(c,j) = 16c + 4w + j + 1, cols 4l..4l+3
    const unsigned colb = ((unsigned)blockIdx.x * 256u + 4u * (unsigned)l) * 4u;
    unsigned voff0 = (unsigned)(4 * w + 1) * ROWB + colb;
    unsigned voff1 = voff0 + ROWB;
    unsigned voff2 = voff0 + 2u * ROWB;
    unsigned voff3 = voff0 + 3u * ROWB;

    float4 d0 = sdt4[0], d1 = sdt4[1], d2 = sdt4[2], d3 = sdt4[3];
    float4 e0, e1, e2, e3;

    #pragma unroll 1
    for (int cc = 0; cc < NCH / 2; ++cc) {
        // ======== even chunk (buf 0, burst set A) ========
        step(d0.x); sbuf[0][ 0][tid] = I;
        step(d0.y); sbuf[0][ 1][tid] = I;
        step(d0.z); sbuf[0][ 2][tid] = I;
        step(d0.w); sbuf[0][ 3][tid] = I;
        step(d1.x); sbuf[0][ 4][tid] = I;
        step(d1.y); sbuf[0][ 5][tid] = I;
        step(d1.z); sbuf[0][ 6][tid] = I;
        step(d1.w); sbuf[0][ 7][tid] = I;
        step(d2.x); sbuf[0][ 8][tid] = I;
        step(d2.y); sbuf[0][ 9][tid] = I;
        step(d2.z); sbuf[0][10][tid] = I;
        step(d2.w); sbuf[0][11][tid] = I;
        step(d3.x); sbuf[0][12][tid] = I;
        step(d3.y); sbuf[0][13][tid] = I;
        step(d3.z); sbuf[0][14][tid] = I;
        step(d3.w); sbuf[0][15][tid] = I;

        asm volatile("s_waitcnt lgkmcnt(0)" ::: "memory");
        __builtin_amdgcn_sched_barrier(0);
        __builtin_amdgcn_s_barrier();       // raw barrier: no vmcnt drain

        // prefetch next chunk's dts (lgkm wait lands at first use)
        e0 = sdt4[8 * cc + 4]; e1 = sdt4[8 * cc + 5];
        e2 = sdt4[8 * cc + 6]; e3 = sdt4[8 * cc + 7];

        // WAR guard for set A (last used 2 chunks ago): only prev chunk's 4
        // stores may still be outstanding
        asm volatile("s_waitcnt vmcnt(4)" ::: "memory");
        __builtin_amdgcn_sched_barrier(0);

        f32x4 sA0 = *(const f32x4*)&sbuf[0][4 * w + 0][4 * l];
        f32x4 sA1 = *(const f32x4*)&sbuf[0][4 * w + 1][4 * l];
        f32x4 sA2 = *(const f32x4*)&sbuf[0][4 * w + 2][4 * l];
        f32x4 sA3 = *(const f32x4*)&sbuf[0][4 * w + 3][4 * l];
        ST4(voff0, sA0);
        ST4(voff1, sA1);
        ST4(voff2, sA2);
        ST4(voff3, sA3);
        voff0 += CH * ROWB; voff1 += CH * ROWB;
        voff2 += CH * ROWB; voff3 += CH * ROWB;

        // ======== odd chunk (buf 1, burst set B) ========
        step(e0.x); sbuf[1][ 0][tid] = I;
        step(e0.y); sbuf[1][ 1][tid] = I;
        step(e0.z); sbuf[1][ 2][tid] = I;
        step(e0.w); sbuf[1][ 3][tid] = I;
        step(e1.x); sbuf[1][ 4][tid] = I;
        step(e1.y); sbuf[1][ 5][tid] = I;
        step(e1.z); sbuf[1][ 6][tid] = I;
        step(e1.w); sbuf[1][ 7][tid] = I;
        step(e2.x); sbuf[1][ 8][tid] = I;
        step(e2.y); sbuf[1][ 9][tid] = I;
        step(e2.z); sbuf[1][10][tid] = I;
        step(e2.w); sbuf[1][11][tid] = I;
        step(e3.x); sbuf[1][12][tid] = I;
        step(e3.y); sbuf[1][13][tid] = I;
        step(e3.z); sbuf[1][14][tid] = I;
        step(e3.w); sbuf[1][15][tid] = I;

        asm volatile("s_waitcnt lgkmcnt(0)" ::: "memory");
        __builtin_amdgcn_sched_barrier(0);
        __builtin_amdgcn_s_barrier();

        d0 = sdt4[8 * cc + 8];  d1 = sdt4[8 * cc + 9];
        d2 = sdt4[8 * cc + 10]; d3 = sdt4[8 * cc + 11];

        asm volatile("s_waitcnt vmcnt(4)" ::: "memory");
        __builtin_amdgcn_sched_barrier(0);

        f32x4 sB0 = *(const f32x4*)&sbuf[1][4 * w + 0][4 * l];
        f32x4 sB1 = *(const f32x4*)&sbuf[1][4 * w + 1][4 * l];
        f32x4 sB2 = *(const f32x4*)&sbuf[1][4 * w + 2][4 * l];
        f32x4 sB3 = *(const f32x4*)&sbuf[1][4 * w + 3][4 * l];
        ST4(voff0, sB0);
        ST4(voff1, sB1);
        ST4(voff2, sB2);
        ST4(voff3, sB3);
        voff0 += CH * ROWB; voff1 += CH * ROWB;
        voff2 += CH * ROWB; voff3 += CH * ROWB;
    }
    // after loop: d0..d3 = sdt[192..207] (zero-padded past 198)

    // ---------- tail: 7 steps -> rows 193..199 ----------
    step(d0.x); sbuf[0][0][tid] = I;
    step(d0.y); sbuf[0][1][tid] = I;
    step(d0.z); sbuf[0][2][tid] = I;
    step(d0.w); sbuf[0][3][tid] = I;
    step(d1.x); sbuf[0][4][tid] = I;
    step(d1.y); sbuf[0][5][tid] = I;
    step(d1.z); sbuf[0][6][tid] = I;

    asm volatile("s_waitcnt lgkmcnt(0)" ::: "memory");
    __builtin_amdgcn_sched_barrier(0);
    __builtin_amdgcn_s_barrier();

    asm volatile("s_waitcnt vmcnt(4)" ::: "memory");
    __builtin_amdgcn_sched_barrier(0);

    // voff_j now = (193 + 4w + j)*ROWB + colb after 12 increments
    if (4 * w + 0 < 7) { f32x4 v = *(const f32x4*)&sbuf[0][4 * w + 0][4 * l]; ST4(voff0, v); }
    if (4 * w + 1 < 7) { f32x4 v = *(const f32x4*)&sbuf[0][4 * w + 1][4 * l]; ST4(voff1, v); }
    if (4 * w + 2 < 7) { f32x4 v = *(const f32x4*)&sbuf[0][4 * w + 2][4 * l]; ST4(voff2, v); }
    if (4 * w + 3 < 7) { f32x4 v = *(const f32x4*)&sbuf[0][4 * w + 3][4 * l]; ST4(voff3, v); }
}

extern "C" void kernel_launch(void* const* d_in, const int* in_sizes, int n_in,
                              void* d_out, int out_size, void* d_ws, size_t ws_size,
                              hipStream_t stream) {
    const float* data  = (const float*)d_in[0];
    const float* times = (const float*)d_in[1];
    const float* W0    = (const float*)d_in[2];
    const float* b0    = (const float*)d_in[3];
    const float* Wh    = (const float*)d_in[4];
    const float* bh    = (const float*)d_in[5];
    const float* Wo    = (const float*)d_in[6];
    const float* bo    = (const float*)d_in[7];
    float* out  = (float*)d_out;
    float* vals = (float*)d_ws;       // 3 * BSZ floats = 768 KB

    dim3 gridA(BSZ / 256, 3);
    mlp_kernel<<<gridA, 256, 0, stream>>>(data, W0, b0, Wh, bh, Wo, bo, vals);
    sir_kernel<<<BSZ / 256, 256, 0, stream>>>(vals, times, out);
}

// Round 12
// 30.721 us; speedup vs baseline: 1.0711x; 1.0711x over previous
//
#include <hip/hip_runtime.h>
#include <math.h>

#define BSZ   65536
#define INP   16
#define HL    10
#define NL    3
#define TT    200
#define NPOP  8600000.0f

#define NCH8  24   // 24 chunks of 8 steps + tail of 7 = 199

__device__ __forceinline__ float fast_tanh(float x) {
    float e = exp2f(x * 2.8853900817779268f);
    return 1.0f - 2.0f * __builtin_amdgcn_rcpf(e + 1.0f);
}

__device__ __forceinline__ float fast_softplus(float x) {
    // max(x,0) + ln2 * log2(1 + 2^(-|x|*log2e))
    float t = exp2f(-fabsf(x) * 1.4426950408889634f);
    return fmaxf(x, 0.0f) + 0.6931471805599453f * log2f(1.0f + t);
}

// ---------------- Kernel A: parameter nets, one thread per (sample, net) ----
__global__ __launch_bounds__(256) void mlp_kernel(
    const float* __restrict__ data,
    const float* __restrict__ W0,  const float* __restrict__ b0,
    const float* __restrict__ Wh,  const float* __restrict__ bh,
    const float* __restrict__ Wo,  const float* __restrict__ bo,
    float* __restrict__ vals)         // 3 x B
{
    const int n   = blockIdx.y;
    const int tid = threadIdx.x;

    __shared__ float sW0[HL * INP];
    __shared__ float sb0[HL];
    __shared__ float sWh[NL * HL * HL];
    __shared__ float sbh[NL * HL];
    __shared__ float sWo[HL];
    __shared__ float sbo;

    for (int i = tid; i < HL * INP;      i += 256) sW0[i] = W0[n * HL * INP + i];
    for (int i = tid; i < HL;            i += 256) sb0[i] = b0[n * HL + i];
    for (int i = tid; i < NL * HL * HL;  i += 256) sWh[i] = Wh[n * NL * HL * HL + i];
    for (int i = tid; i < NL * HL;       i += 256) sbh[i] = bh[n * NL * HL + i];
    for (int i = tid; i < HL;            i += 256) sWo[i] = Wo[n * HL + i];
    if (tid == 0) sbo = bo[n];
    __syncthreads();

    const int b = blockIdx.x * 256 + tid;

    float x[INP];
    const float4* xin = reinterpret_cast<const float4*>(data + (size_t)b * INP);
    #pragma unroll
    for (int q = 0; q < INP / 4; ++q) {
        float4 v = xin[q];
        x[q * 4 + 0] = v.x; x[q * 4 + 1] = v.y;
        x[q * 4 + 2] = v.z; x[q * 4 + 3] = v.w;
    }

    float h[HL];
    #pragma unroll
    for (int k = 0; k < HL; ++k) {
        float acc = sb0[k];
        #pragma unroll
        for (int i = 0; i < INP; ++i)
            acc = fmaf(x[i], sW0[k * INP + i], acc);
        h[k] = fast_tanh(acc);
    }
    #pragma unroll
    for (int l = 0; l < NL; ++l) {
        float h2[HL];
        #pragma unroll
        for (int k = 0; k < HL; ++k) {
            float acc = sbh[l * HL + k];
            #pragma unroll
            for (int i = 0; i < HL; ++i)
                acc = fmaf(h[i], sWh[(l * HL + k) * HL + i], acc);
            h2[k] = fast_tanh(acc);
        }
        #pragma unroll
        for (int k = 0; k < HL; ++k) h[k] = h2[k];
    }
    float acc = sbo;
    #pragma unroll
    for (int i = 0; i < HL; ++i)
        acc = fmaf(h[i], sWo[i], acc);

    vals[(size_t)n * BSZ + b] = fast_softplus(acc);
}

// ---------------- Kernel B: RK4 integration, P = bn*S state fold ------------
__global__ __launch_bounds__(64, 1) void sir_kernel(
    const float* __restrict__ vals,   // 3 x B
    const float* __restrict__ times,  // T
    float* __restrict__ out)          // T x B
{
    const int tid = threadIdx.x;
    const int b   = blockIdx.x * 64 + tid;

    const float g    = vals[b];           // gamma
    const float beta = vals[BSZ + b];
    const float I0   = vals[2 * BSZ + b];

    __shared__ float sdt[208];        // 52 float4s, zero-padded past 198
    for (int i = tid; i < 208; i += 64)
        sdt[i] = (i < TT - 1) ? (times[i + 1] - times[i]) : 0.0f;
    __syncthreads();

    const float bn = beta * (1.0f / NPOP);
    float I = I0;
    float P = bn * (NPOP - I0);       // P tracks bn*S

    // t = 0 row via asm store: compiler can't vmcnt-guard I's register
    {
        unsigned v0 = (unsigned)b * 4u;
        asm volatile("global_store_dword %0, %1, %2"
                     :: "v"(v0), "v"(I), "s"(out) : "memory");
    }

    // depth-14 step: f = P*I at depth 1, m via single fmaf, coefs off-chain
    auto step = [&](float dt) {
        const float hdt = 0.5f * dt;
        const float hb  = bn * hdt;
        const float db  = bn * dt;
        const float c6  = dt * (1.0f / 6.0f);
        const float cb  = bn * c6;
        float f1 = P * I;
        float m1 = fmaf(-g, I, f1);
        float aP = fmaf(-hb, f1, P);
        float aI = fmaf(hdt, m1, I);
        float f2 = aP * aI;
        float m2 = fmaf(-g, aI, f2);
        float bP = fmaf(-hb, f2, P);
        float bI = fmaf(hdt, m2, I);
        float f3 = bP * bI;
        float m3 = fmaf(-g, bI, f3);
        float cP = fmaf(-db, f3, P);
        float cI = fmaf(dt, m3, I);
        float f4 = cP * cI;
        float m4 = fmaf(-g, cI, f4);
        float s1 = m1 + m4;
        float s2 = m2 + m3;
        float u1 = f1 + f4;
        float u2 = f2 + f3;
        I = fmaf(c6, fmaf(2.0f, s2, s1), I);
        P = fmaf(-cb, fmaf(2.0f, u2, u1), P);
    };

    const float4* sdt4 = reinterpret_cast<const float4*>(sdt);

    float4 da = sdt4[0];
    float4 db4 = sdt4[1];
    float* op = out + BSZ;            // row t = 1

    #pragma unroll 1
    for (int gch = 0; gch < NCH8; ++gch) {
        // prefetch next chunk's dts; lgkm wait lands at the da/db4 copy below
        float4 na = sdt4[2 * gch + 2];
        float4 nb = sdt4[2 * gch + 3];
        __builtin_amdgcn_sched_barrier(0);

        float ic0, ic1, ic2, ic3, ic4, ic5, ic6, ic7;
        step(da.x);  ic0 = I; op[b          ] = ic0;
        step(da.y);  ic1 = I; op[b + 1 * BSZ] = ic1;
        step(da.z);  ic2 = I; op[b + 2 * BSZ] = ic2;
        step(da.w);  ic3 = I; op[b + 3 * BSZ] = ic3;
        step(db4.x); ic4 = I; op[b + 4 * BSZ] = ic4;
        step(db4.y); ic5 = I; op[b + 5 * BSZ] = ic5;
        step(db4.z); ic6 = I; op[b + 6 * BSZ] = ic6;
        step(db4.w); ic7 = I; op[b + 7 * BSZ] = ic7;

        // 8 distinct live store-data regs -> reuse distance ~7 steps
        asm volatile("" :: "v"(ic0), "v"(ic1), "v"(ic2), "v"(ic3),
                           "v"(ic4), "v"(ic5), "v"(ic6), "v"(ic7));

        da = na; db4 = nb;
        op += 8 * BSZ;
    }

    // tail: 7 steps (t = 192..198)
    {
        float d0 = sdt[192], d1 = sdt[193], d2 = sdt[194], d3 = sdt[195];
        float d4 = sdt[196], d5 = sdt[197], d6 = sdt[198];
        float ic0, ic1, ic2, ic3, ic4, ic5, ic6;
        step(d0); ic0 = I; op[b          ] = ic0;
        step(d1); ic1 = I; op[b + 1 * BSZ] = ic1;
        step(d2); ic2 = I; op[b + 2 * BSZ] = ic2;
        step(d3); ic3 = I; op[b + 3 * BSZ] = ic3;
        step(d4); ic4 = I; op[b + 4 * BSZ] = ic4;
        step(d5); ic5 = I; op[b + 5 * BSZ] = ic5;
        step(d6); ic6 = I; op[b + 6 * BSZ] = ic6;
        asm volatile("" :: "v"(ic0), "v"(ic1), "v"(ic2), "v"(ic3),
                           "v"(ic4), "v"(ic5), "v"(ic6));
    }
}

extern "C" void kernel_launch(void* const* d_in, const int* in_sizes, int n_in,
                              void* d_out, int out_size, void* d_ws, size_t ws_size,
                              hipStream_t stream) {
    const float* data  = (const float*)d_in[0];
    const float* times = (const float*)d_in[1];
    const float* W0    = (const float*)d_in[2];
    const float* b0    = (const float*)d_in[3];
    const float* Wh    = (const float*)d_in[4];
    const float* bh    = (const float*)d_in[5];
    const float* Wo    = (const float*)d_in[6];
    const float* bo    = (const float*)d_in[7];
    float* out  = (float*)d_out;
    float* vals = (float*)d_ws;       // 3 * BSZ floats = 768 KB

    dim3 gridA(BSZ / 256, 3);
    mlp_kernel<<<gridA, 256, 0, stream>>>(data, W0, b0, Wh, bh, Wo, bo, vals);
    sir_kernel<<<BSZ / 64, 64, 0, stream>>>(vals, times, out);
}